// Round 1
// baseline (695.726 us; speedup 1.0000x reference)
//
#include <hip/hip_runtime.h>

// ---------------------------------------------------------------------------
// GCN: out = spmm(A, relu(spmm(A, x)@w1 + b1)) @ w2 + b2
// Reordered (spmm commutes with right-mul):
//   y1 = x@w1 ; h1 = relu(spmm(y1)+b1) ; y2 = h1@w2 ; out = spmm(y2)+b2
// CSR built per-launch via counting sort (hist -> scan -> scatter).
// ---------------------------------------------------------------------------

// ---- histogram ------------------------------------------------------------
__global__ void hist_kernel(const int* __restrict__ row, int* __restrict__ counts, int E) {
    int i = blockIdx.x * blockDim.x + threadIdx.x;
    if (i < E) atomicAdd(&counts[row[i]], 1);
}

// ---- exclusive scan (1024 elems/block, 256 thr x 4) -----------------------
__global__ void scan_a(const int* __restrict__ in, int* __restrict__ out,
                       int* __restrict__ bsums, int n) {
    __shared__ int lds[256];
    const int t = threadIdx.x;
    const int base = blockIdx.x * 1024 + t * 4;
    int v[4];
    int s = 0;
#pragma unroll
    for (int j = 0; j < 4; ++j) {
        v[j] = (base + j < n) ? in[base + j] : 0;
        s += v[j];
    }
    lds[t] = s;
    __syncthreads();
    // Hillis-Steele inclusive scan over 256 thread-sums
    for (int off = 1; off < 256; off <<= 1) {
        int tmp = 0;
        if (t >= off) tmp = lds[t - off];
        __syncthreads();
        if (t >= off) lds[t] += tmp;
        __syncthreads();
    }
    int prefix = (t > 0) ? lds[t - 1] : 0;
    int run = prefix;
#pragma unroll
    for (int j = 0; j < 4; ++j) {
        if (base + j < n) out[base + j] = run;
        run += v[j];
    }
    if (t == 255) bsums[blockIdx.x] = lds[255];
}

__global__ void scan_b(int* __restrict__ bsums, int nb) {
    __shared__ int lds[128];
    const int t = threadIdx.x;  // 128 threads
    int v = (t < nb) ? bsums[t] : 0;
    lds[t] = v;
    __syncthreads();
    for (int off = 1; off < 128; off <<= 1) {
        int tmp = 0;
        if (t >= off) tmp = lds[t - off];
        __syncthreads();
        if (t >= off) lds[t] += tmp;
        __syncthreads();
    }
    if (t < nb) bsums[t] = (t > 0) ? lds[t - 1] : 0;
}

__global__ void scan_c(int* __restrict__ rowptr, int* __restrict__ cursor,
                       const int* __restrict__ bsums, int n, int total) {
    int i = blockIdx.x * blockDim.x + threadIdx.x;
    if (i < n) {
        int val = rowptr[i] + bsums[i >> 10];
        rowptr[i] = val;
        cursor[i] = val;
    }
    if (i == 0) rowptr[n] = total;
}

// ---- scatter edges into row-sorted order ----------------------------------
__global__ void scatter_kernel(const int* __restrict__ row, const int* __restrict__ col,
                               const float* __restrict__ val, int* __restrict__ cursor,
                               int* __restrict__ colS, float* __restrict__ valS, int E) {
    int i = blockIdx.x * blockDim.x + threadIdx.x;
    if (i < E) {
        int r = row[i];
        int pos = atomicAdd(&cursor[r], 1);
        colS[pos] = col[i];
        valS[pos] = val[i];
    }
}

// ---- dense GEMM: y[M x NC] = x[M x 128] @ w[128 x NC] ---------------------
// block: 256 thr, 64 rows/block. thread(cg=tid&15, rg=tid>>4): 4 rows x NC/16 cols
// (cyclic col assignment c = cg + 16*ci -> conflict-free LDS broadcast reads)
template <int NC>
__global__ __launch_bounds__(256) void gemm_kernel(const float* __restrict__ x,
                                                   const float* __restrict__ w,
                                                   float* __restrict__ y, int M) {
    constexpr int TC = NC / 16;
    __shared__ float wl[128 * NC];
    const int tid = threadIdx.x;
    for (int i = tid * 4; i < 128 * NC; i += 1024) {
        *(float4*)&wl[i] = *(const float4*)&w[i];
    }
    __syncthreads();
    const int cg = tid & 15;
    const int rg = tid >> 4;
    const int row0 = blockIdx.x * 64 + rg * 4;
    float acc[4][TC] = {};
    int r[4];
#pragma unroll
    for (int ri = 0; ri < 4; ++ri) r[ri] = min(row0 + ri, M - 1);
    for (int k4 = 0; k4 < 128; k4 += 4) {
        float xv[4][4];
#pragma unroll
        for (int ri = 0; ri < 4; ++ri)
            *(float4*)xv[ri] = *(const float4*)&x[(size_t)r[ri] * 128 + k4];
#pragma unroll
        for (int kk = 0; kk < 4; ++kk) {
            float wv[TC];
#pragma unroll
            for (int ci = 0; ci < TC; ++ci) wv[ci] = wl[(k4 + kk) * NC + cg + 16 * ci];
#pragma unroll
            for (int ri = 0; ri < 4; ++ri)
#pragma unroll
                for (int ci = 0; ci < TC; ++ci)
                    acc[ri][ci] += xv[ri][kk] * wv[ci];
        }
    }
#pragma unroll
    for (int ri = 0; ri < 4; ++ri) {
        int row = row0 + ri;
        if (row < M) {
#pragma unroll
            for (int ci = 0; ci < TC; ++ci)
                y[(size_t)row * NC + cg + 16 * ci] = acc[ri][ci];
        }
    }
}

// ---- SPMM: out[r] = sum_e val[e]*y[col[e]] (+bias, opt relu). wave/row ----
template <int CH, bool RELU>
__global__ __launch_bounds__(256) void spmm_kernel(const int* __restrict__ rowptr,
                                                   const int* __restrict__ colS,
                                                   const float* __restrict__ valS,
                                                   const float* __restrict__ y,
                                                   const float* __restrict__ bias,
                                                   float* __restrict__ out, int n) {
    const int wid = (blockIdx.x * 256 + threadIdx.x) >> 6;
    const int lane = threadIdx.x & 63;
    if (wid >= n) return;
    const int s = rowptr[wid];
    const int e = rowptr[wid + 1];
    if constexpr (CH == 128) {
        const float2* y2 = (const float2*)y;
        float accx = 0.f, accy = 0.f;
        for (int i = s; i < e; ++i) {
            int c = colS[i];
            float v = valS[i];
            float2 xv = y2[(size_t)c * 64 + lane];
            accx += v * xv.x;
            accy += v * xv.y;
        }
        float2 bv = ((const float2*)bias)[lane];
        accx += bv.x;
        accy += bv.y;
        if (RELU) {
            accx = fmaxf(accx, 0.f);
            accy = fmaxf(accy, 0.f);
        }
        float2 o;
        o.x = accx;
        o.y = accy;
        ((float2*)out)[(size_t)wid * 64 + lane] = o;
    } else {
        float acc = 0.f;
        for (int i = s; i < e; ++i) {
            int c = colS[i];
            float v = valS[i];
            acc += v * y[(size_t)c * 64 + lane];
        }
        acc += bias[lane];
        if (RELU) acc = fmaxf(acc, 0.f);
        out[(size_t)wid * 64 + lane] = acc;
    }
}

// ---------------------------------------------------------------------------
extern "C" void kernel_launch(void* const* d_in, const int* in_sizes, int n_in,
                              void* d_out, int out_size, void* d_ws, size_t ws_size,
                              hipStream_t stream) {
    const float* x    = (const float*)d_in[0];
    const int*   arow = (const int*)d_in[1];
    const int*   acol = (const int*)d_in[2];
    const float* aval = (const float*)d_in[3];
    const float* w1   = (const float*)d_in[4];
    const float* b1   = (const float*)d_in[5];
    const float* w2   = (const float*)d_in[6];
    const float* b2   = (const float*)d_in[7];
    float*       out  = (float*)d_out;

    const int N = in_sizes[0] / 128;  // 100000
    const int E = in_sizes[1];        // 1600000

    // workspace carve-up (256B aligned)
    char* p = (char*)d_ws;
    auto alloc = [&](size_t bytes) {
        char* r = p;
        p += (bytes + 255) & ~(size_t)255;
        return r;
    };
    int*   counts = (int*)alloc((size_t)N * 4);        // also scan input
    int*   rowptr = (int*)alloc((size_t)(N + 1) * 4);
    int*   cursor = (int*)alloc((size_t)N * 4);
    int*   bsums  = (int*)alloc(128 * 4);
    int*   colS   = (int*)alloc((size_t)E * 4);
    float* valS   = (float*)alloc((size_t)E * 4);
    float* y1     = (float*)alloc((size_t)N * 128 * 4);
    float* h1     = (float*)alloc((size_t)N * 128 * 4);
    float* y2     = y1;  // reuse: y1 dead after spmm1

    // ---- build CSR (counting sort) ----
    hipMemsetAsync(counts, 0, (size_t)N * 4, stream);
    hist_kernel<<<(E + 255) / 256, 256, 0, stream>>>(arow, counts, E);
    const int nb = (N + 1023) / 1024;  // 98
    scan_a<<<nb, 256, 0, stream>>>(counts, rowptr, bsums, N);
    scan_b<<<1, 128, 0, stream>>>(bsums, nb);
    scan_c<<<(N + 255) / 256, 256, 0, stream>>>(rowptr, cursor, bsums, N, E);
    scatter_kernel<<<(E + 255) / 256, 256, 0, stream>>>(arow, acol, aval, cursor, colS, valS, E);

    // ---- layer 1: y1 = x@w1 ; h1 = relu(spmm(y1)+b1) ----
    const int gemm_blocks = (N + 63) / 64;
    gemm_kernel<128><<<gemm_blocks, 256, 0, stream>>>(x, w1, y1, N);
    const int spmm_blocks = (N + 3) / 4;  // 4 waves/block, 1 row/wave
    spmm_kernel<128, true><<<spmm_blocks, 256, 0, stream>>>(rowptr, colS, valS, y1, b1, h1, N);

    // ---- layer 2: y2 = h1@w2 ; out = spmm(y2)+b2 ----
    gemm_kernel<64><<<gemm_blocks, 256, 0, stream>>>(h1, w2, y2, N);
    spmm_kernel<64, false><<<spmm_blocks, 256, 0, stream>>>(rowptr, colS, valS, y2, b2, out, N);
}

// Round 2
// 531.586 us; speedup vs baseline: 1.3088x; 1.3088x over previous
//
#include <hip/hip_runtime.h>

// ---------------------------------------------------------------------------
// GCN: out = spmm(A, relu(spmm(A, x)@w1 + b1)) @ w2 + b2
// Reordered: y1 = x@w1 ; h1 = relu(spmm(y1)+b1) ; y2 = h1@w2 ; out = spmm(y2)+b2
// R2: bf16 intermediates (y1,h1,y2 in bf16 -> gather targets fit L2) and
//     bf16 MFMA GEMMs (16x16x32). CSR built per-launch via counting sort.
// ---------------------------------------------------------------------------

typedef __bf16 v8bf __attribute__((ext_vector_type(8)));
typedef float  v4f  __attribute__((ext_vector_type(4)));

__device__ __forceinline__ unsigned short f2bf(float f) {
    unsigned u = __float_as_uint(f);
    unsigned r = u + 0x7fffu + ((u >> 16) & 1u);   // RNE
    return (unsigned short)(r >> 16);
}

// ---- histogram ------------------------------------------------------------
__global__ void hist_kernel(const int* __restrict__ row, int* __restrict__ counts, int E) {
    int i = blockIdx.x * blockDim.x + threadIdx.x;
    if (i < E) atomicAdd(&counts[row[i]], 1);
}

// ---- exclusive scan (1024 elems/block, 256 thr x 4) -----------------------
__global__ void scan_a(const int* __restrict__ in, int* __restrict__ out,
                       int* __restrict__ bsums, int n) {
    __shared__ int lds[256];
    const int t = threadIdx.x;
    const int base = blockIdx.x * 1024 + t * 4;
    int v[4];
    int s = 0;
#pragma unroll
    for (int j = 0; j < 4; ++j) {
        v[j] = (base + j < n) ? in[base + j] : 0;
        s += v[j];
    }
    lds[t] = s;
    __syncthreads();
    for (int off = 1; off < 256; off <<= 1) {
        int tmp = 0;
        if (t >= off) tmp = lds[t - off];
        __syncthreads();
        if (t >= off) lds[t] += tmp;
        __syncthreads();
    }
    int prefix = (t > 0) ? lds[t - 1] : 0;
    int run = prefix;
#pragma unroll
    for (int j = 0; j < 4; ++j) {
        if (base + j < n) out[base + j] = run;
        run += v[j];
    }
    if (t == 255) bsums[blockIdx.x] = lds[255];
}

__global__ void scan_b(int* __restrict__ bsums, int nb) {
    __shared__ int lds[128];
    const int t = threadIdx.x;
    int v = (t < nb) ? bsums[t] : 0;
    lds[t] = v;
    __syncthreads();
    for (int off = 1; off < 128; off <<= 1) {
        int tmp = 0;
        if (t >= off) tmp = lds[t - off];
        __syncthreads();
        if (t >= off) lds[t] += tmp;
        __syncthreads();
    }
    if (t < nb) bsums[t] = (t > 0) ? lds[t - 1] : 0;
}

__global__ void scan_c(int* __restrict__ rowptr, int* __restrict__ cursor,
                       const int* __restrict__ bsums, int n, int total) {
    int i = blockIdx.x * blockDim.x + threadIdx.x;
    if (i < n) {
        int val = rowptr[i] + bsums[i >> 10];
        rowptr[i] = val;
        cursor[i] = val;
    }
    if (i == 0) rowptr[n] = total;
}

// ---- scatter edges into row-sorted order ----------------------------------
__global__ void scatter_kernel(const int* __restrict__ row, const int* __restrict__ col,
                               const float* __restrict__ val, int* __restrict__ cursor,
                               int* __restrict__ colS, float* __restrict__ valS, int E) {
    int i = blockIdx.x * blockDim.x + threadIdx.x;
    if (i < E) {
        int r = row[i];
        int pos = atomicAdd(&cursor[r], 1);
        colS[pos] = col[i];
        valS[pos] = val[i];
    }
}

// ---- cast + transpose weights: w[K][NC] fp32 -> wT[NC][K] bf16 ------------
__global__ void cast_transpose_w(const float* __restrict__ w, unsigned short* __restrict__ wT,
                                 int K, int NC) {
    int i = blockIdx.x * blockDim.x + threadIdx.x;
    if (i < K * NC) {
        int k = i / NC, n = i - k * NC;
        wT[n * K + k] = f2bf(w[i]);
    }
}

// ---- MFMA GEMM: y_bf16[M x NC] = A[M x 128] @ W[128 x NC] -----------------
// block = 256 thr = 4 waves; 16 rows/wave, 64 rows/block. W^T staged in LDS
// (padded stride 136 -> 2-way bank aliasing only). A read from global
// (fp32 fused-convert for layer 1, bf16 direct for layer 2).
template <int NC, bool AF32>
__global__ __launch_bounds__(256) void gemm_mfma(const void* __restrict__ A,
                                                 const unsigned short* __restrict__ wT,
                                                 unsigned short* __restrict__ y, int M) {
    constexpr int KP = 136;           // padded K stride (bf16 elems)
    constexpr int NT = NC / 16;       // n-tiles per wave
    __shared__ unsigned short wl[NC * KP];
    const int tid = threadIdx.x;
    // stage W^T: NC rows x 128 k, 16B chunks
    for (int idx = tid; idx < NC * 16; idx += 256) {
        int n = idx >> 4, kc = idx & 15;
        *(uint4*)&wl[n * KP + kc * 8] = *(const uint4*)&wT[n * 128 + kc * 8];
    }
    __syncthreads();

    const int wave = tid >> 6;
    const int lane = tid & 63;
    const int m = lane & 15;          // A-row / D-col index
    const int q = lane >> 4;          // k-quad / D-row-quad
    const int rowbase = blockIdx.x * 64 + wave * 16;
    const int rowc = min(rowbase + m, M - 1);

    v4f acc[NT] = {};
    union LU { uint4 qv; v8bf b; };

#pragma unroll
    for (int ks = 0; ks < 4; ++ks) {
        const int k0 = ks * 32 + q * 8;
        v8bf a;
        if (AF32) {
            const float* Ap = (const float*)A + (size_t)rowc * 128 + k0;
            float4 f0 = *(const float4*)Ap;
            float4 f1 = *(const float4*)(Ap + 4);
            union { unsigned short s[8]; v8bf b; } cv;
            cv.s[0] = f2bf(f0.x); cv.s[1] = f2bf(f0.y);
            cv.s[2] = f2bf(f0.z); cv.s[3] = f2bf(f0.w);
            cv.s[4] = f2bf(f1.x); cv.s[5] = f2bf(f1.y);
            cv.s[6] = f2bf(f1.z); cv.s[7] = f2bf(f1.w);
            a = cv.b;
        } else {
            LU lu;
            lu.qv = *(const uint4*)((const unsigned short*)A + (size_t)rowc * 128 + k0);
            a = lu.b;
        }
#pragma unroll
        for (int nt = 0; nt < NT; ++nt) {
            v8bf b = *(const v8bf*)&wl[(nt * 16 + m) * KP + k0];
            acc[nt] = __builtin_amdgcn_mfma_f32_16x16x32_bf16(a, b, acc[nt], 0, 0, 0);
        }
    }
    // epilogue: D row = 4q+r (local), col = 16*nt + m
#pragma unroll
    for (int nt = 0; nt < NT; ++nt) {
#pragma unroll
        for (int r = 0; r < 4; ++r) {
            int orow = rowbase + q * 4 + r;
            if (orow < M) y[(size_t)orow * NC + nt * 16 + m] = f2bf(acc[nt][r]);
        }
    }
}

// ---- SPMM: out[r] = sum_e val[e]*y[col[e]] (+bias, opt relu) --------------
// one wave per row; bf16 gather target. CH=128: lane covers ch {2l,2l+1} via
// one dword. CH=64: lane covers ch l via ushort. col/val prefetched 64-wide
// and broadcast by shuffle.
template <int CH, bool RELU, bool OUT_BF16>
__global__ __launch_bounds__(256) void spmm_b(const int* __restrict__ rowptr,
                                              const int* __restrict__ colS,
                                              const float* __restrict__ valS,
                                              const unsigned short* __restrict__ yb,
                                              const float* __restrict__ bias,
                                              void* __restrict__ out, int n) {
    const int wid = (blockIdx.x * 256 + threadIdx.x) >> 6;
    const int lane = threadIdx.x & 63;
    if (wid >= n) return;
    const int s = rowptr[wid];
    const int e = rowptr[wid + 1];
    float accx = 0.f, accy = 0.f;
    for (int base = s; base < e; base += 64) {
        const int idx = base + lane;
        int c = 0; float v = 0.f;
        if (idx < e) { c = colS[idx]; v = valS[idx]; }
        const int cnt = min(64, e - base);
        for (int j = 0; j < cnt; ++j) {
            int cc = __shfl(c, j, 64);
            float vv = __shfl(v, j, 64);
            if (CH == 128) {
                unsigned u = ((const unsigned*)yb)[(size_t)cc * 64 + lane];
                accx += vv * __uint_as_float(u << 16);
                accy += vv * __uint_as_float(u & 0xffff0000u);
            } else {
                unsigned u = yb[(size_t)cc * 64 + lane];
                accx += vv * __uint_as_float(u << 16);
            }
        }
    }
    if (CH == 128) {
        float2 bv = ((const float2*)bias)[lane];
        accx += bv.x; accy += bv.y;
        if (RELU) { accx = fmaxf(accx, 0.f); accy = fmaxf(accy, 0.f); }
        if (OUT_BF16) {
            unsigned pk = ((unsigned)f2bf(accy) << 16) | f2bf(accx);
            ((unsigned*)out)[(size_t)wid * 64 + lane] = pk;
        } else {
            float2 o; o.x = accx; o.y = accy;
            ((float2*)out)[(size_t)wid * 64 + lane] = o;
        }
    } else {
        accx += bias[lane];
        if (RELU) accx = fmaxf(accx, 0.f);
        if (OUT_BF16) {
            ((unsigned short*)out)[(size_t)wid * 64 + lane] = f2bf(accx);
        } else {
            ((float*)out)[(size_t)wid * 64 + lane] = accx;
        }
    }
}

// ---------------------------------------------------------------------------
extern "C" void kernel_launch(void* const* d_in, const int* in_sizes, int n_in,
                              void* d_out, int out_size, void* d_ws, size_t ws_size,
                              hipStream_t stream) {
    const float* x    = (const float*)d_in[0];
    const int*   arow = (const int*)d_in[1];
    const int*   acol = (const int*)d_in[2];
    const float* aval = (const float*)d_in[3];
    const float* w1   = (const float*)d_in[4];
    const float* b1   = (const float*)d_in[5];
    const float* w2   = (const float*)d_in[6];
    const float* b2   = (const float*)d_in[7];
    float*       out  = (float*)d_out;

    const int N = in_sizes[0] / 128;  // 100000
    const int E = in_sizes[1];        // 1600000

    char* p = (char*)d_ws;
    auto alloc = [&](size_t bytes) {
        char* r = p;
        p += (bytes + 255) & ~(size_t)255;
        return r;
    };
    int*            counts = (int*)alloc((size_t)N * 4);
    int*            rowptr = (int*)alloc((size_t)(N + 1) * 4);
    int*            cursor = (int*)alloc((size_t)N * 4);
    int*            bsums  = (int*)alloc(128 * 4);
    int*            colS   = (int*)alloc((size_t)E * 4);
    float*          valS   = (float*)alloc((size_t)E * 4);
    unsigned short* w1T    = (unsigned short*)alloc(128 * 128 * 2);
    unsigned short* w2T    = (unsigned short*)alloc(64 * 128 * 2);
    unsigned short* y1b    = (unsigned short*)alloc((size_t)N * 128 * 2);
    unsigned short* h1b    = (unsigned short*)alloc((size_t)N * 128 * 2);
    unsigned short* y2b    = (unsigned short*)alloc((size_t)N * 64 * 2);

    // ---- build CSR (counting sort) ----
    hipMemsetAsync(counts, 0, (size_t)N * 4, stream);
    hist_kernel<<<(E + 255) / 256, 256, 0, stream>>>(arow, counts, E);
    const int nb = (N + 1023) / 1024;
    scan_a<<<nb, 256, 0, stream>>>(counts, rowptr, bsums, N);
    scan_b<<<1, 128, 0, stream>>>(bsums, nb);
    scan_c<<<(N + 255) / 256, 256, 0, stream>>>(rowptr, cursor, bsums, N, E);
    scatter_kernel<<<(E + 255) / 256, 256, 0, stream>>>(arow, acol, aval, cursor, colS, valS, E);

    // ---- weight casts ----
    cast_transpose_w<<<(128 * 128 + 255) / 256, 256, 0, stream>>>(w1, w1T, 128, 128);
    cast_transpose_w<<<(128 * 64 + 255) / 256, 256, 0, stream>>>(w2, w2T, 128, 64);

    // ---- layer 1 ----
    const int gemm_blocks = (N + 63) / 64;
    gemm_mfma<128, true><<<gemm_blocks, 256, 0, stream>>>(x, w1T, y1b, N);
    const int spmm_blocks = (N + 3) / 4;
    spmm_b<128, true, true><<<spmm_blocks, 256, 0, stream>>>(rowptr, colS, valS, y1b, b1, h1b, N);

    // ---- layer 2 ----
    gemm_mfma<64, false><<<gemm_blocks, 256, 0, stream>>>(h1b, w2T, y2b, N);
    spmm_b<64, false, false><<<spmm_blocks, 256, 0, stream>>>(rowptr, colS, valS, y2b, b2, out, N);
}